// Round 9
// baseline (394.560 us; speedup 1.0000x reference)
//
#include <hip/hip_runtime.h>
#include <hip/hip_bf16.h>

#define STEPS 100
#define DTC 0.001f

typedef __attribute__((ext_vector_type(8))) short bf16x8;
typedef __attribute__((ext_vector_type(4))) float f32x4;

__device__ __forceinline__ void gload16(const void* g, void* l) {
  __builtin_amdgcn_global_load_lds(
      (const __attribute__((address_space(1))) void*)g,
      (__attribute__((address_space(3))) void*)l,
      16, 0, 0);
}

// ---------------- prep: fused front (4 rows/block, weight-reuse) + all tpacks ------
// Blocks 0..63: front for batch rows 4b..4b+3 (enc1+enc2+enc3+hopf, fp32).
// Blocks 64..4415: one 32x32 transpose tile each (job table as rounds 5-8).
// front blocks launch first (long pole); tpack tiles fill the remaining CUs.

__constant__ int    jSrcC[10] = {0, 1, 1, 0, 2, 3, 3, 2, 4, 5};
__constant__ float  jSgnC[10] = {1.f, 1.f, -1.f, 1.f, 1.f, 1.f, -1.f, 1.f, 1.f, -1.f};
__constant__ int    jCC[10]   = {1024, 1024, 1024, 1024, 512, 512, 512, 512, 256, 256};
__constant__ int    jDstC[10] = {0, 0, 0, 0, 1, 1, 1, 1, 2, 2};
__constant__ int    jDsC[10]  = {1024, 1024, 1024, 1024, 2048, 2048, 2048, 2048, 1024, 1024};
__constant__ long   jOffC[10] = {0, 1048576, 512, 1049088, 0, 1048576, 1024, 1049600, 0, 512};

__global__ __launch_bounds__(512)
void prep(const float* __restrict__ ms_in, const float* __restrict__ rs_in,
          const float* __restrict__ z,
          const float* __restrict__ Wms, const float* __restrict__ bms,
          const float* __restrict__ Wrs, const float* __restrict__ brs,
          const float* __restrict__ Wc, const float* __restrict__ bc,
          const float* __restrict__ Wmu, const float* __restrict__ bmu,
          const float* __restrict__ Wb, const float* __restrict__ bbias,
          const float* __restrict__ Wom, const float* __restrict__ bom,
          const float* __restrict__ Wr0, const float* __restrict__ Wi0,
          const float* __restrict__ Wr1, const float* __restrict__ Wi1,
          const float* __restrict__ Wr2, const float* __restrict__ Wi2,
          __hip_bfloat16* __restrict__ BT0, __hip_bfloat16* __restrict__ BT1,
          __hip_bfloat16* __restrict__ BT2,
          __hip_bfloat16* __restrict__ A0, float* __restrict__ z_out,
          float* __restrict__ om_out, float* __restrict__ mu_out,
          float* __restrict__ bb_out) {
  const int bid = blockIdx.x;
  const int tid = threadIdx.x;  // 512

  if (bid < 64) {
    // ---------------- front: 4 batch rows, weights loaded once, used 4x ----------
    __shared__ float sIn[4][192];
    __shared__ float stA[4][512];
    __shared__ float stB[4][512];
    const int b4 = bid * 4;
    const int n = tid;
#pragma unroll
    for (int r = 0; r < 4; ++r) {
      if (n < 64) sIn[r][n] = ms_in[(b4 + r) * 64 + n];
      else if (n < 192) sIn[r][n] = rs_in[(b4 + r) * 128 + (n - 64)];
    }
    __syncthreads();
    // enc1
    float a[4];
    if (n < 256) {
      const float bias = bms[n];
#pragma unroll
      for (int r = 0; r < 4; ++r) a[r] = bias;
      for (int k = 0; k < 64; ++k) {
        const float wv = Wms[k * 256 + n];
#pragma unroll
        for (int r = 0; r < 4; ++r) a[r] += sIn[r][k] * wv;
      }
    } else {
      const int nn = n - 256;
      const float bias = brs[nn];
#pragma unroll
      for (int r = 0; r < 4; ++r) a[r] = bias;
      for (int k = 0; k < 128; ++k) {
        const float wv = Wrs[k * 256 + nn];
#pragma unroll
        for (int r = 0; r < 4; ++r) a[r] += sIn[r][64 + k] * wv;
      }
    }
#pragma unroll
    for (int r = 0; r < 4; ++r) stA[r][n] = fmaxf(a[r], 0.f);
    __syncthreads();
    // enc2
    float c[4];
    {
      const float bias = bc[n];
#pragma unroll
      for (int r = 0; r < 4; ++r) c[r] = bias;
      for (int k = 0; k < 512; ++k) {
        const float wv = Wc[k * 512 + n];
#pragma unroll
        for (int r = 0; r < 4; ++r) c[r] += stA[r][k] * wv;
      }
    }
#pragma unroll
    for (int r = 0; r < 4; ++r) stB[r][n] = fmaxf(c[r], 0.f);
    __syncthreads();
    // enc3: mu, b
    float am[4], ab[4];
    {
      const float bm = bmu[n], bb2 = bbias[n];
#pragma unroll
      for (int r = 0; r < 4; ++r) { am[r] = bm; ab[r] = bb2; }
      for (int k = 0; k < 512; ++k) {
        const float wm = Wmu[k * 512 + n];
        const float wb = Wb[k * 512 + n];
#pragma unroll
        for (int r = 0; r < 4; ++r) {
          am[r] += stB[r][k] * wm;
          ab[r] += stB[r][k] * wb;
        }
      }
    }
    float muv[4], bbv[4];
#pragma unroll
    for (int r = 0; r < 4; ++r) {
      muv[r] = fabsf(fmaxf(am[r], 0.f));
      bbv[r] = fabsf(fmaxf(ab[r], 0.f));
      mu_out[(b4 + r) * 512 + n] = muv[r];
      bb_out[(b4 + r) * 512 + n] = bbv[r];
    }
    // omega: 4 tree-reductions in parallel (stA reused as reduction buffer)
    {
      const float wo = Wom[n];
#pragma unroll
      for (int r = 0; r < 4; ++r) stA[r][n] = stB[r][n] * wo;
    }
    __syncthreads();
    for (int off = 256; off > 0; off >>= 1) {
      if (n < off) {
#pragma unroll
        for (int r = 0; r < 4; ++r) stA[r][n] += stA[r][n + off];
      }
      __syncthreads();
    }
    float om[4];
#pragma unroll
    for (int r = 0; r < 4; ++r) {
      om[r] = fabsf(fmaxf(stA[r][0] + bom[0], 0.f));
      if (n == 0) om_out[b4 + r] = om[r];
    }
    // hopf trajectory x4 rows (fp32 state; bf16 GEMM input, m = b*100 + t)
    float xx[4], yy[4], ww[4];
#pragma unroll
    for (int r = 0; r < 4; ++r) {
      xx[r] = z[(b4 + r) * 1024 + n];
      yy[r] = z[(b4 + r) * 1024 + 512 + n];
      ww[r] = om[r] * (float)(n + 1);
    }
    for (int t = 0; t < STEPS; ++t) {
#pragma unroll
      for (int r = 0; r < 4; ++r) {
        const float r2 = xx[r] * xx[r] + yy[r] * yy[r];
        const float g = muv[r] - r2;
        const float nx = xx[r] + DTC * (g * xx[r] - ww[r] * yy[r] + bbv[r]);
        const float ny = yy[r] + DTC * (g * yy[r] + ww[r] * xx[r]);
        xx[r] = nx; yy[r] = ny;
        if (t == 0) {
          z_out[(b4 + r) * 1024 + n] = nx;
          z_out[(b4 + r) * 1024 + 512 + n] = ny;
        }
        const size_t row = (size_t)(b4 + r) * STEPS + t;
        A0[row * 1024 + n] = __float2bfloat16(nx);
        A0[row * 1024 + 512 + n] = __float2bfloat16(ny);
      }
    }
  } else {
    // ---------------- tpack: one 32x32 transpose tile per block (512 thr) --------
    __shared__ float tile[32][33];
    const int t = bid - 64;
    int j, w;
    if (t < 4096) { j = t >> 9; w = t & 511; }
    else          { j = 8 + ((t - 4096) >> 7); w = (t - 4096) & 127; }
    const float* srcs[6] = {Wr0, Wi0, Wr1, Wi1, Wr2, Wi2};
    __hip_bfloat16* dsts[3] = {BT0, BT1, BT2};
    const float* src = srcs[jSrcC[j]];
    __hip_bfloat16* dst = dsts[jDstC[j]] + jOffC[j];
    const int C = jCC[j], ds = jDsC[j];
    const float sign = jSgnC[j];
    const int ncb = C >> 5;
    const int cb = (w % ncb) * 32, rb = (w / ncb) * 32;
    const int tx = tid & 31, ty = tid >> 5;  // (32,16)
#pragma unroll
    for (int i = 0; i < 32; i += 16)
      tile[ty + i][tx] = src[(size_t)(rb + ty + i) * C + (cb + tx)];
    __syncthreads();
#pragma unroll
    for (int i = 0; i < 32; i += 16)
      dst[(size_t)(cb + ty + i) * ds + (rb + tx)] = __float2bfloat16(sign * tile[tx][ty + i]);
  }
}

// ---------------- 160x128 bf16 MFMA GEMM, exact-grid (unchanged from round 8) ----
// BM=160, BN=128, BK=64; 256 threads = 4 waves (2Mx2N), per-wave 80x64.
// G1 2560 = 10x256 exact, G2 1280 = 5x256 exact. LDS 72KiB -> 2 blocks/CU.
// Pre-swizzled source + XOR read (rule #21); 4-phase vmcnt(2)/counted lgkmcnt.

#define SBAR __builtin_amdgcn_sched_barrier(0)

#define RD_A(DST, QX, cb) do { _Pragma("unroll") for (int mi = 0; mi < 5; ++mi) \
  DST[mi] = *(const bf16x8*)((cb) + (abase ^ ((QX) * 64)) + mi * 2048); } while (0)

#define RD_B(DST, h, QX, cb) do { _Pragma("unroll") for (int jj = 0; jj < 2; ++jj) \
  DST[jj] = *(const bf16x8*)((cb) + (bbase ^ ((QX) * 64)) + (2 * (h) + jj) * 2048); } while (0)

#define MF_PH(ASET, BSET, h) do { _Pragma("unroll") for (int mi = 0; mi < 5; ++mi) \
  _Pragma("unroll") for (int jj = 0; jj < 2; ++jj) \
    acc[mi][2 * (h) + jj] = __builtin_amdgcn_mfma_f32_16x16x32_bf16( \
        ASET[mi], BSET[jj], acc[mi][2 * (h) + jj], 0, 0, 0); } while (0)

template <int OUT_BF16>
__global__ __launch_bounds__(256, 2)
void gemm160(const __hip_bfloat16* __restrict__ A, const __hip_bfloat16* __restrict__ BT,
             const float* __restrict__ biasA, const float* __restrict__ biasB, int bsplit,
             void* __restrict__ Cout, int N, int K, int ntn_l2) {
  extern __shared__ char lds[];  // 73728 B: 2 buf x (A 20480 | B 16384)

  const int tid = threadIdx.x;
  const int lane = tid & 63;
  const int wid = tid >> 6;       // 0..3
  const int wr = wid >> 1;        // M half (80 rows)
  const int wc = wid & 1;         // N half (64 cols)
  const int fr = lane & 15, fq = lane >> 4;

  // XCD-aware bijective swizzle (all grids here are %8==0)
  const int nwg = gridDim.x;
  int f = blockIdx.x;
  f = (f & 7) * (nwg >> 3) + (f >> 3);
  const int m0 = (f >> ntn_l2) * 160;
  const int n0 = (f & ((1 << ntn_l2) - 1)) << 7;

  // staging source (pre-swizzled chunk): thread t covers rows rA+32j, chunk c8v
  const int rA = tid >> 3;                  // 0..31
  const int c8v = (tid & 7) ^ (rA & 7);
  const __hip_bfloat16* Asrc = A + (size_t)(m0 + rA) * K + c8v * 8;
  const __hip_bfloat16* Bsrc = BT + (size_t)(n0 + rA) * K + c8v * 8;

  // swizzled LDS read offsets (byte): slot = row*8 + ((fq+4q) ^ (row&7));
  // 80/64/16 are all %8==0 so row&7 == fr&7.
  const int x0 = fq ^ (fr & 7);
  const int abase = (wr * 80 + fr) * 128 + x0 * 16;           // + mi*2048; ^64 for q=1
  const int bbase = 20480 + (wc * 64 + fr) * 128 + x0 * 16;   // + nj*2048; ^64 for q=1

  auto stgA = [&](int j, int ko, char* buf) {
    gload16(Asrc + ko + (size_t)32 * j * K, buf + j * 4096 + wid * 1024);
  };
  auto stgB = [&](int j, int ko, char* buf) {
    gload16(Bsrc + ko + (size_t)32 * j * K, buf + 20480 + j * 4096 + wid * 1024);
  };

  // prologue: tile 0 -> buf 0 (9 loads in flight)
  stgA(0, 0, lds); stgA(1, 0, lds); stgA(2, 0, lds); stgA(3, 0, lds); stgA(4, 0, lds);
  stgB(0, 0, lds); stgB(1, 0, lds); stgB(2, 0, lds); stgB(3, 0, lds);

  f32x4 acc[5][4] = {};
  bf16x8 a0[5], a1[5], b00[2], b10[2], b01[2], b11[2];

  const int nk = K >> 6;
  for (int kt = 0; kt < nk - 1; ++kt) {
    char* cb = lds + (kt & 1) * 36864;
    char* nb = lds + ((kt & 1) ^ 1) * 36864;
    const int ko = (kt + 1) << 6;
    // ---- phase 0: stage A0,A1(next); vmcnt(2) -> cur tile landed; MFMA (h0,q0)
    __builtin_amdgcn_s_barrier();            // all waves done reading 'nb'
    SBAR;
    stgA(0, ko, nb); stgA(1, ko, nb);
    SBAR;
    asm volatile("s_waitcnt vmcnt(2)" ::: "memory");  // cur's 9 loads landed; 2 new in flight
    __builtin_amdgcn_s_barrier();            // cur visible to all waves
    SBAR;
    RD_A(a0, 0, cb);        // 5 ds_read_b128
    RD_B(b00, 0, 0, cb);    // 2
    SBAR;                   // pin order before b10
    RD_B(b10, 1, 0, cb);    // 2 (for phase 1)
    asm volatile("s_waitcnt lgkmcnt(2)" ::: "memory");  // a0+b00 done; b10 in flight
    SBAR;
    __builtin_amdgcn_s_setprio(1); MF_PH(a0, b00, 0); __builtin_amdgcn_s_setprio(0);
    // ---- phase 1: stage A2..A4; issue q1 A-reads + b01; MFMA (h1,q0)
    __builtin_amdgcn_s_barrier();
    SBAR;
    stgA(2, ko, nb); stgA(3, ko, nb); stgA(4, ko, nb);
    RD_A(a1, 1, cb);        // 5 (for phases 2-3)
    RD_B(b01, 0, 1, cb);    // 2 (for phase 2)
    asm volatile("s_waitcnt lgkmcnt(7)" ::: "memory");  // b10 done; a1+b01 in flight
    SBAR;
    __builtin_amdgcn_s_setprio(1); MF_PH(a0, b10, 1); __builtin_amdgcn_s_setprio(0);
    // ---- phase 2: stage B0,B1; issue b11; MFMA (h0,q1)
    __builtin_amdgcn_s_barrier();
    SBAR;
    stgB(0, ko, nb); stgB(1, ko, nb);
    RD_B(b11, 1, 1, cb);    // 2 (for phase 3)
    asm volatile("s_waitcnt lgkmcnt(2)" ::: "memory");  // a1+b01 done; b11 in flight
    SBAR;
    __builtin_amdgcn_s_setprio(1); MF_PH(a1, b01, 0); __builtin_amdgcn_s_setprio(0);
    // ---- phase 3: stage B2,B3; MFMA (h1,q1)
    __builtin_amdgcn_s_barrier();
    SBAR;
    stgB(2, ko, nb); stgB(3, ko, nb);
    asm volatile("s_waitcnt lgkmcnt(0)" ::: "memory");
    SBAR;
    __builtin_amdgcn_s_setprio(1); MF_PH(a1, b11, 1); __builtin_amdgcn_s_setprio(0);
  }
  // ---- final tile: compute-only (no staging -> no stray loads)
  {
    char* cb = lds + ((nk - 1) & 1) * 36864;
    __builtin_amdgcn_s_barrier();
    asm volatile("s_waitcnt vmcnt(0)" ::: "memory");
    __builtin_amdgcn_s_barrier();
    SBAR;
    RD_A(a0, 0, cb);
    RD_B(b00, 0, 0, cb);
    SBAR;
    RD_B(b10, 1, 0, cb);
    asm volatile("s_waitcnt lgkmcnt(2)" ::: "memory");
    SBAR;
    __builtin_amdgcn_s_setprio(1); MF_PH(a0, b00, 0); __builtin_amdgcn_s_setprio(0);
    RD_A(a1, 1, cb);
    RD_B(b01, 0, 1, cb);
    asm volatile("s_waitcnt lgkmcnt(7)" ::: "memory");
    SBAR;
    __builtin_amdgcn_s_setprio(1); MF_PH(a0, b10, 1); __builtin_amdgcn_s_setprio(0);
    RD_B(b11, 1, 1, cb);
    asm volatile("s_waitcnt lgkmcnt(2)" ::: "memory");
    SBAR;
    __builtin_amdgcn_s_setprio(1); MF_PH(a1, b01, 0); __builtin_amdgcn_s_setprio(0);
    asm volatile("s_waitcnt lgkmcnt(0)" ::: "memory");
    SBAR;
    __builtin_amdgcn_s_setprio(1); MF_PH(a1, b11, 1); __builtin_amdgcn_s_setprio(0);
  }

  // epilogue: bias + relu. C/D layout: col=lane&15, row=(lane>>4)*4+reg
#pragma unroll
  for (int nj = 0; nj < 4; ++nj) {
    const int col = n0 + wc * 64 + nj * 16 + fr;
    const float bv = (col < bsplit) ? biasA[col] : biasB[col - bsplit];
#pragma unroll
    for (int mi = 0; mi < 5; ++mi) {
#pragma unroll
      for (int r = 0; r < 4; ++r) {
        const int row = m0 + wr * 80 + mi * 16 + fq * 4 + r;
        float v = fmaxf(acc[mi][nj][r] + bv, 0.f);
        if (OUT_BF16)
          ((__hip_bfloat16*)Cout)[(size_t)row * N + col] = __float2bfloat16(v);
        else
          ((float*)Cout)[(size_t)row * N + col] = v;
      }
    }
  }
}

// ---------------- launch ----------------

extern "C" void kernel_launch(void* const* d_in, const int* in_sizes, int n_in,
                              void* d_out, int out_size, void* d_ws, size_t ws_size,
                              hipStream_t stream) {
  const float* motion = (const float*)d_in[0];
  const float* robot  = (const float*)d_in[1];
  const float* z      = (const float*)d_in[2];
  const float* W_ms   = (const float*)d_in[3];
  const float* b_ms   = (const float*)d_in[4];
  const float* W_rs   = (const float*)d_in[5];
  const float* b_rs   = (const float*)d_in[6];
  const float* W_cmb  = (const float*)d_in[7];
  const float* b_cmb  = (const float*)d_in[8];
  const float* W_om   = (const float*)d_in[9];
  const float* b_om   = (const float*)d_in[10];
  const float* W_mu   = (const float*)d_in[11];
  const float* b_mu   = (const float*)d_in[12];
  const float* W_b    = (const float*)d_in[13];
  const float* b_b    = (const float*)d_in[14];
  const float* Wr0    = (const float*)d_in[15];
  const float* Wi0    = (const float*)d_in[16];
  const float* br0    = (const float*)d_in[17];
  const float* bi0    = (const float*)d_in[18];
  const float* Wr1    = (const float*)d_in[19];
  const float* Wi1    = (const float*)d_in[20];
  const float* br1    = (const float*)d_in[21];
  const float* bi1    = (const float*)d_in[22];
  const float* Wr2    = (const float*)d_in[23];
  const float* Wi2    = (const float*)d_in[24];
  const float* br2    = (const float*)d_in[25];
  // bi2 (d_in[26]) unused: yi of last layer is sliced away by [:, :, :256]

  float* out  = (float*)d_out;            // [25600,256], m = b*100+t
  float* zout = out + (size_t)6553600;    // [256,1024]
  float* omg  = zout + 262144;            // [256]
  float* muo  = omg + 256;                // [256,512]
  float* bbo  = muo + 131072;             // [256,512]

  char* ws = (char*)d_ws;
  __hip_bfloat16* BT0 = (__hip_bfloat16*)ws;               // [2048,1024]
  __hip_bfloat16* BT1 = BT0 + (size_t)2048 * 1024;         // [1024,2048]
  __hip_bfloat16* BT2 = BT1 + (size_t)1024 * 2048;         // [256,1024]
  __hip_bfloat16* A0  = BT2 + (size_t)256 * 1024;          // [25600,1024]
  __hip_bfloat16* C1  = A0 + (size_t)25600 * 1024;         // [25600,2048]
  __hip_bfloat16* C2  = C1 + (size_t)25600 * 2048;         // [25600,1024]

  // fused front (64 blocks, 4 rows each) + 10 weight transposes (4352 tiles)
  prep<<<4416, 512, 0, stream>>>(motion, robot, z, W_ms, b_ms, W_rs, b_rs,
                                 W_cmb, b_cmb, W_mu, b_mu, W_b, b_b, W_om, b_om,
                                 Wr0, Wi0, Wr1, Wi1, Wr2, Wi2, BT0, BT1, BT2,
                                 A0, zout, omg, muo, bbo);

  // GEMM1: [25600,1024] x [2048,1024]^T -> C1 bf16   (160x16 = 2560 = 10x256 exact)
  gemm160<1><<<2560, 256, 73728, stream>>>(A0, BT0, br0, bi0, 1024, C1, 2048, 1024, 4);
  // GEMM2: [25600,2048] x [1024,2048]^T -> C2 bf16   (160x8 = 1280 = 5x256 exact)
  gemm160<1><<<1280, 256, 73728, stream>>>(C1, BT1, br1, bi1, 512, C2, 1024, 2048, 3);
  // GEMM3: [25600,1024] x [256,1024]^T -> out f32    (160x2 = 320 tiles)
  gemm160<0><<<320, 256, 73728, stream>>>(C2, BT2, br2, br2, 256, out, 256, 1024, 1);
}

// Round 10
// 271.853 us; speedup vs baseline: 1.4514x; 1.4514x over previous
//
#include <hip/hip_runtime.h>
#include <hip/hip_bf16.h>

#define STEPS 100
#define DTC 0.001f

typedef __attribute__((ext_vector_type(8))) short bf16x8;
typedef __attribute__((ext_vector_type(4))) float f32x4;

__device__ __forceinline__ void gload16(const void* g, void* l) {
  __builtin_amdgcn_global_load_lds(
      (const __attribute__((address_space(1))) void*)g,
      (__attribute__((address_space(3))) void*)l,
      16, 0, 0);
}

// ---------------- prep: front (1 row/block, 2-way k-split, 1024 thr) + tpacks ------
// Blocks 0..255: front for batch row b. Threads (n = tid&511, h = tid>>9); the
// 512-deep matvecs are split k<256 / k>=256 across h -> half the serial chain,
// double the waves/SIMD (fixes r9's measured latency stall: VALUBusy 5.8%).
// Blocks 256..4607: one 32x32 transpose tile each (job table as rounds 5-9).

__constant__ int    jSrcC[10] = {0, 1, 1, 0, 2, 3, 3, 2, 4, 5};
__constant__ float  jSgnC[10] = {1.f, 1.f, -1.f, 1.f, 1.f, 1.f, -1.f, 1.f, 1.f, -1.f};
__constant__ int    jCC[10]   = {1024, 1024, 1024, 1024, 512, 512, 512, 512, 256, 256};
__constant__ int    jDstC[10] = {0, 0, 0, 0, 1, 1, 1, 1, 2, 2};
__constant__ int    jDsC[10]  = {1024, 1024, 1024, 1024, 2048, 2048, 2048, 2048, 1024, 1024};
__constant__ long   jOffC[10] = {0, 1048576, 512, 1049088, 0, 1048576, 1024, 1049600, 0, 512};

__global__ __launch_bounds__(1024)
void prep(const float* __restrict__ ms_in, const float* __restrict__ rs_in,
          const float* __restrict__ z,
          const float* __restrict__ Wms, const float* __restrict__ bms,
          const float* __restrict__ Wrs, const float* __restrict__ brs,
          const float* __restrict__ Wc, const float* __restrict__ bc,
          const float* __restrict__ Wmu, const float* __restrict__ bmu,
          const float* __restrict__ Wb, const float* __restrict__ bbias,
          const float* __restrict__ Wom, const float* __restrict__ bom,
          const float* __restrict__ Wr0, const float* __restrict__ Wi0,
          const float* __restrict__ Wr1, const float* __restrict__ Wi1,
          const float* __restrict__ Wr2, const float* __restrict__ Wi2,
          __hip_bfloat16* __restrict__ BT0, __hip_bfloat16* __restrict__ BT1,
          __hip_bfloat16* __restrict__ BT2,
          __hip_bfloat16* __restrict__ A0, float* __restrict__ z_out,
          float* __restrict__ om_out, float* __restrict__ mu_out,
          float* __restrict__ bb_out) {
  const int bid = blockIdx.x;
  const int tid = threadIdx.x;  // 1024

  if (bid < 256) {
    // ---------------- front: one batch row, k-split matvecs ----------------
    __shared__ float sIn[192];
    __shared__ float stA[512];
    __shared__ float stB[512];
    __shared__ float pA[2][512];
    __shared__ float pB[2][512];
    const int b = bid;
    const int n = tid & 511;
    const int h = tid >> 9;
    if (h == 0) {
      if (n < 64) sIn[n] = ms_in[b * 64 + n];
      else if (n < 192) sIn[n] = rs_in[b * 128 + (n - 64)];
    }
    __syncthreads();
    // enc1 (half 0 only; k is small) -- identical order to round 8
    if (h == 0) {
      float a1;
      if (n < 256) {
        a1 = bms[n];
        for (int k = 0; k < 64; ++k) a1 += sIn[k] * Wms[k * 256 + n];
      } else {
        const int nn = n - 256;
        a1 = brs[nn];
        for (int k = 0; k < 128; ++k) a1 += sIn[64 + k] * Wrs[k * 256 + nn];
      }
      stA[n] = fmaxf(a1, 0.f);
    }
    __syncthreads();
    // enc2: k-split partial sums
    {
      float p = (h == 0) ? bc[n] : 0.f;
      const int k0 = h << 8;
      for (int k = 0; k < 256; ++k) p += stA[k0 + k] * Wc[(k0 + k) * 512 + n];
      pA[h][n] = p;
    }
    __syncthreads();
    if (h == 0) stB[n] = fmaxf(pA[0][n] + pA[1][n], 0.f);
    __syncthreads();
    // enc3: mu and b, k-split
    {
      float pm = (h == 0) ? bmu[n] : 0.f;
      float pb = (h == 0) ? bbias[n] : 0.f;
      const int k0 = h << 8;
      for (int k = 0; k < 256; ++k) {
        const float sv = stB[k0 + k];
        pm += sv * Wmu[(k0 + k) * 512 + n];
        pb += sv * Wb[(k0 + k) * 512 + n];
      }
      pA[h][n] = pm;
      pB[h][n] = pb;
    }
    __syncthreads();
    float muv = 0.f, bbv = 0.f;
    if (h == 0) {
      muv = fabsf(fmaxf(pA[0][n] + pA[1][n], 0.f));
      bbv = fabsf(fmaxf(pB[0][n] + pB[1][n], 0.f));
      mu_out[b * 512 + n] = muv;
      bb_out[b * 512 + n] = bbv;
    }
    __syncthreads();  // pA free; reuse for omega reduction
    if (h == 0) pA[0][n] = stB[n] * Wom[n];
    __syncthreads();
    for (int off = 256; off > 0; off >>= 1) {
      if (h == 0 && n < off) pA[0][n] += pA[0][n + off];
      __syncthreads();
    }
    const float om = fabsf(fmaxf(pA[0][0] + bom[0], 0.f));
    if (tid == 0) om_out[b] = om;
    // hopf trajectory on half 0 (fp32 state; bf16 GEMM input, m = b*100 + t)
    if (h == 0) {
      float x = z[b * 1024 + n];
      float y = z[b * 1024 + 512 + n];
      const float w = om * (float)(n + 1);
      for (int t = 0; t < STEPS; ++t) {
        const float r2 = x * x + y * y;
        const float g = muv - r2;
        const float nx = x + DTC * (g * x - w * y + bbv);
        const float ny = y + DTC * (g * y + w * x);
        x = nx; y = ny;
        if (t == 0) {
          z_out[b * 1024 + n] = x;
          z_out[b * 1024 + 512 + n] = y;
        }
        const size_t row = (size_t)b * STEPS + t;
        A0[row * 1024 + n] = __float2bfloat16(x);
        A0[row * 1024 + 512 + n] = __float2bfloat16(y);
      }
    }
  } else {
    // ---------------- tpack: one 32x32 transpose tile per block (1024 thr) -------
    __shared__ float tile[32][33];
    const int t = bid - 256;
    int j, w;
    if (t < 4096) { j = t >> 9; w = t & 511; }
    else          { j = 8 + ((t - 4096) >> 7); w = (t - 4096) & 127; }
    const float* srcs[6] = {Wr0, Wi0, Wr1, Wi1, Wr2, Wi2};
    __hip_bfloat16* dsts[3] = {BT0, BT1, BT2};
    const float* src = srcs[jSrcC[j]];
    __hip_bfloat16* dst = dsts[jDstC[j]] + jOffC[j];
    const int C = jCC[j], ds = jDsC[j];
    const float sign = jSgnC[j];
    const int ncb = C >> 5;
    const int cb = (w % ncb) * 32, rb = (w / ncb) * 32;
    const int tx = tid & 31, ty = tid >> 5;  // (32,32)
    tile[ty][tx] = src[(size_t)(rb + ty) * C + (cb + tx)];
    __syncthreads();
    dst[(size_t)(cb + ty) * ds + (rb + tx)] = __float2bfloat16(sign * tile[tx][ty]);
  }
}

// ---------------- 160x128 bf16 MFMA GEMM, exact-grid (unchanged from round 8) ----
// BM=160, BN=128, BK=64; 256 threads = 4 waves (2Mx2N), per-wave 80x64.
// G1 2560 = 10x256 exact, G2 1280 = 5x256 exact. LDS 72KiB -> 2 blocks/CU.
// Pre-swizzled source + XOR read (rule #21); 4-phase vmcnt(2)/counted lgkmcnt.

#define SBAR __builtin_amdgcn_sched_barrier(0)

#define RD_A(DST, QX, cb) do { _Pragma("unroll") for (int mi = 0; mi < 5; ++mi) \
  DST[mi] = *(const bf16x8*)((cb) + (abase ^ ((QX) * 64)) + mi * 2048); } while (0)

#define RD_B(DST, h, QX, cb) do { _Pragma("unroll") for (int jj = 0; jj < 2; ++jj) \
  DST[jj] = *(const bf16x8*)((cb) + (bbase ^ ((QX) * 64)) + (2 * (h) + jj) * 2048); } while (0)

#define MF_PH(ASET, BSET, h) do { _Pragma("unroll") for (int mi = 0; mi < 5; ++mi) \
  _Pragma("unroll") for (int jj = 0; jj < 2; ++jj) \
    acc[mi][2 * (h) + jj] = __builtin_amdgcn_mfma_f32_16x16x32_bf16( \
        ASET[mi], BSET[jj], acc[mi][2 * (h) + jj], 0, 0, 0); } while (0)

template <int OUT_BF16>
__global__ __launch_bounds__(256, 2)
void gemm160(const __hip_bfloat16* __restrict__ A, const __hip_bfloat16* __restrict__ BT,
             const float* __restrict__ biasA, const float* __restrict__ biasB, int bsplit,
             void* __restrict__ Cout, int N, int K, int ntn_l2) {
  extern __shared__ char lds[];  // 73728 B: 2 buf x (A 20480 | B 16384)

  const int tid = threadIdx.x;
  const int lane = tid & 63;
  const int wid = tid >> 6;       // 0..3
  const int wr = wid >> 1;        // M half (80 rows)
  const int wc = wid & 1;         // N half (64 cols)
  const int fr = lane & 15, fq = lane >> 4;

  // XCD-aware bijective swizzle (all grids here are %8==0)
  const int nwg = gridDim.x;
  int f = blockIdx.x;
  f = (f & 7) * (nwg >> 3) + (f >> 3);
  const int m0 = (f >> ntn_l2) * 160;
  const int n0 = (f & ((1 << ntn_l2) - 1)) << 7;

  // staging source (pre-swizzled chunk): thread t covers rows rA+32j, chunk c8v
  const int rA = tid >> 3;                  // 0..31
  const int c8v = (tid & 7) ^ (rA & 7);
  const __hip_bfloat16* Asrc = A + (size_t)(m0 + rA) * K + c8v * 8;
  const __hip_bfloat16* Bsrc = BT + (size_t)(n0 + rA) * K + c8v * 8;

  // swizzled LDS read offsets (byte): slot = row*8 + ((fq+4q) ^ (row&7));
  // 80/64/16 are all %8==0 so row&7 == fr&7.
  const int x0 = fq ^ (fr & 7);
  const int abase = (wr * 80 + fr) * 128 + x0 * 16;           // + mi*2048; ^64 for q=1
  const int bbase = 20480 + (wc * 64 + fr) * 128 + x0 * 16;   // + nj*2048; ^64 for q=1

  auto stgA = [&](int j, int ko, char* buf) {
    gload16(Asrc + ko + (size_t)32 * j * K, buf + j * 4096 + wid * 1024);
  };
  auto stgB = [&](int j, int ko, char* buf) {
    gload16(Bsrc + ko + (size_t)32 * j * K, buf + 20480 + j * 4096 + wid * 1024);
  };

  // prologue: tile 0 -> buf 0 (9 loads in flight)
  stgA(0, 0, lds); stgA(1, 0, lds); stgA(2, 0, lds); stgA(3, 0, lds); stgA(4, 0, lds);
  stgB(0, 0, lds); stgB(1, 0, lds); stgB(2, 0, lds); stgB(3, 0, lds);

  f32x4 acc[5][4] = {};
  bf16x8 a0[5], a1[5], b00[2], b10[2], b01[2], b11[2];

  const int nk = K >> 6;
  for (int kt = 0; kt < nk - 1; ++kt) {
    char* cb = lds + (kt & 1) * 36864;
    char* nb = lds + ((kt & 1) ^ 1) * 36864;
    const int ko = (kt + 1) << 6;
    // ---- phase 0: stage A0,A1(next); vmcnt(2) -> cur tile landed; MFMA (h0,q0)
    __builtin_amdgcn_s_barrier();            // all waves done reading 'nb'
    SBAR;
    stgA(0, ko, nb); stgA(1, ko, nb);
    SBAR;
    asm volatile("s_waitcnt vmcnt(2)" ::: "memory");  // cur's 9 loads landed; 2 new in flight
    __builtin_amdgcn_s_barrier();            // cur visible to all waves
    SBAR;
    RD_A(a0, 0, cb);        // 5 ds_read_b128
    RD_B(b00, 0, 0, cb);    // 2
    SBAR;                   // pin order before b10
    RD_B(b10, 1, 0, cb);    // 2 (for phase 1)
    asm volatile("s_waitcnt lgkmcnt(2)" ::: "memory");  // a0+b00 done; b10 in flight
    SBAR;
    __builtin_amdgcn_s_setprio(1); MF_PH(a0, b00, 0); __builtin_amdgcn_s_setprio(0);
    // ---- phase 1: stage A2..A4; issue q1 A-reads + b01; MFMA (h1,q0)
    __builtin_amdgcn_s_barrier();
    SBAR;
    stgA(2, ko, nb); stgA(3, ko, nb); stgA(4, ko, nb);
    RD_A(a1, 1, cb);        // 5 (for phases 2-3)
    RD_B(b01, 0, 1, cb);    // 2 (for phase 2)
    asm volatile("s_waitcnt lgkmcnt(7)" ::: "memory");  // b10 done; a1+b01 in flight
    SBAR;
    __builtin_amdgcn_s_setprio(1); MF_PH(a0, b10, 1); __builtin_amdgcn_s_setprio(0);
    // ---- phase 2: stage B0,B1; issue b11; MFMA (h0,q1)
    __builtin_amdgcn_s_barrier();
    SBAR;
    stgB(0, ko, nb); stgB(1, ko, nb);
    RD_B(b11, 1, 1, cb);    // 2 (for phase 3)
    asm volatile("s_waitcnt lgkmcnt(2)" ::: "memory");  // a1+b01 done; b11 in flight
    SBAR;
    __builtin_amdgcn_s_setprio(1); MF_PH(a1, b01, 0); __builtin_amdgcn_s_setprio(0);
    // ---- phase 3: stage B2,B3; MFMA (h1,q1)
    __builtin_amdgcn_s_barrier();
    SBAR;
    stgB(2, ko, nb); stgB(3, ko, nb);
    asm volatile("s_waitcnt lgkmcnt(0)" ::: "memory");
    SBAR;
    __builtin_amdgcn_s_setprio(1); MF_PH(a1, b11, 1); __builtin_amdgcn_s_setprio(0);
  }
  // ---- final tile: compute-only (no staging -> no stray loads)
  {
    char* cb = lds + ((nk - 1) & 1) * 36864;
    __builtin_amdgcn_s_barrier();
    asm volatile("s_waitcnt vmcnt(0)" ::: "memory");
    __builtin_amdgcn_s_barrier();
    SBAR;
    RD_A(a0, 0, cb);
    RD_B(b00, 0, 0, cb);
    SBAR;
    RD_B(b10, 1, 0, cb);
    asm volatile("s_waitcnt lgkmcnt(2)" ::: "memory");
    SBAR;
    __builtin_amdgcn_s_setprio(1); MF_PH(a0, b00, 0); __builtin_amdgcn_s_setprio(0);
    RD_A(a1, 1, cb);
    RD_B(b01, 0, 1, cb);
    asm volatile("s_waitcnt lgkmcnt(7)" ::: "memory");
    SBAR;
    __builtin_amdgcn_s_setprio(1); MF_PH(a0, b10, 1); __builtin_amdgcn_s_setprio(0);
    RD_B(b11, 1, 1, cb);
    asm volatile("s_waitcnt lgkmcnt(2)" ::: "memory");
    SBAR;
    __builtin_amdgcn_s_setprio(1); MF_PH(a1, b01, 0); __builtin_amdgcn_s_setprio(0);
    asm volatile("s_waitcnt lgkmcnt(0)" ::: "memory");
    SBAR;
    __builtin_amdgcn_s_setprio(1); MF_PH(a1, b11, 1); __builtin_amdgcn_s_setprio(0);
  }

  // epilogue: bias + relu. C/D layout: col=lane&15, row=(lane>>4)*4+reg
#pragma unroll
  for (int nj = 0; nj < 4; ++nj) {
    const int col = n0 + wc * 64 + nj * 16 + fr;
    const float bv = (col < bsplit) ? biasA[col] : biasB[col - bsplit];
#pragma unroll
    for (int mi = 0; mi < 5; ++mi) {
#pragma unroll
      for (int r = 0; r < 4; ++r) {
        const int row = m0 + wr * 80 + mi * 16 + fq * 4 + r;
        float v = fmaxf(acc[mi][nj][r] + bv, 0.f);
        if (OUT_BF16)
          ((__hip_bfloat16*)Cout)[(size_t)row * N + col] = __float2bfloat16(v);
        else
          ((float*)Cout)[(size_t)row * N + col] = v;
      }
    }
  }
}

// ---------------- launch ----------------

extern "C" void kernel_launch(void* const* d_in, const int* in_sizes, int n_in,
                              void* d_out, int out_size, void* d_ws, size_t ws_size,
                              hipStream_t stream) {
  const float* motion = (const float*)d_in[0];
  const float* robot  = (const float*)d_in[1];
  const float* z      = (const float*)d_in[2];
  const float* W_ms   = (const float*)d_in[3];
  const float* b_ms   = (const float*)d_in[4];
  const float* W_rs   = (const float*)d_in[5];
  const float* b_rs   = (const float*)d_in[6];
  const float* W_cmb  = (const float*)d_in[7];
  const float* b_cmb  = (const float*)d_in[8];
  const float* W_om   = (const float*)d_in[9];
  const float* b_om   = (const float*)d_in[10];
  const float* W_mu   = (const float*)d_in[11];
  const float* b_mu   = (const float*)d_in[12];
  const float* W_b    = (const float*)d_in[13];
  const float* b_b    = (const float*)d_in[14];
  const float* Wr0    = (const float*)d_in[15];
  const float* Wi0    = (const float*)d_in[16];
  const float* br0    = (const float*)d_in[17];
  const float* bi0    = (const float*)d_in[18];
  const float* Wr1    = (const float*)d_in[19];
  const float* Wi1    = (const float*)d_in[20];
  const float* br1    = (const float*)d_in[21];
  const float* bi1    = (const float*)d_in[22];
  const float* Wr2    = (const float*)d_in[23];
  const float* Wi2    = (const float*)d_in[24];
  const float* br2    = (const float*)d_in[25];
  // bi2 (d_in[26]) unused: yi of last layer is sliced away by [:, :, :256]

  float* out  = (float*)d_out;            // [25600,256], m = b*100+t
  float* zout = out + (size_t)6553600;    // [256,1024]
  float* omg  = zout + 262144;            // [256]
  float* muo  = omg + 256;                // [256,512]
  float* bbo  = muo + 131072;             // [256,512]

  char* ws = (char*)d_ws;
  __hip_bfloat16* BT0 = (__hip_bfloat16*)ws;               // [2048,1024]
  __hip_bfloat16* BT1 = BT0 + (size_t)2048 * 1024;         // [1024,2048]
  __hip_bfloat16* BT2 = BT1 + (size_t)1024 * 2048;         // [256,1024]
  __hip_bfloat16* A0  = BT2 + (size_t)256 * 1024;          // [25600,1024]
  __hip_bfloat16* C1  = A0 + (size_t)25600 * 1024;         // [25600,2048]
  __hip_bfloat16* C2  = C1 + (size_t)25600 * 2048;         // [25600,1024]

  // front (256 blocks, 1 row, k-split) + 10 weight transposes (4352 tiles)
  prep<<<4608, 1024, 0, stream>>>(motion, robot, z, W_ms, b_ms, W_rs, b_rs,
                                  W_cmb, b_cmb, W_mu, b_mu, W_b, b_b, W_om, b_om,
                                  Wr0, Wi0, Wr1, Wi1, Wr2, Wi2, BT0, BT1, BT2,
                                  A0, zout, omg, muo, bbo);

  // GEMM1: [25600,1024] x [2048,1024]^T -> C1 bf16   (160x16 = 2560 = 10x256 exact)
  gemm160<1><<<2560, 256, 73728, stream>>>(A0, BT0, br0, bi0, 1024, C1, 2048, 1024, 4);
  // GEMM2: [25600,2048] x [1024,2048]^T -> C2 bf16   (160x8 = 1280 = 5x256 exact)
  gemm160<1><<<1280, 256, 73728, stream>>>(C1, BT1, br1, bi1, 512, C2, 1024, 2048, 3);
  // GEMM3: [25600,1024] x [256,1024]^T -> out f32    (160x2 = 320 tiles)
  gemm160<0><<<320, 256, 73728, stream>>>(C2, BT2, br2, br2, 256, out, 256, 1024, 1);
}